// Round 9
// baseline (103.897 us; speedup 1.0000x reference)
//
#include <hip/hip_runtime.h>

#define PL 128
#define STRIDE 64
#define WSZ 16

typedef float f32x4 __attribute__((ext_vector_type(4)));

// R8 fill-replica structure, single variable changed: grid 256 -> 512
// (2 blocks/CU, 8 waves/CU, lockstep window 2 MB). Tests whether per-CU
// memory-level parallelism (in-flight store count) was the limiter at 4
// waves/CU. Mapping invariant: T = gridDim.x*256 f32x4 must be ≡ 0 mod 4096
// (patch size) and grid ≡ 0 mod 16 -> each thread's within-patch offset is
// loop-invariant: chunk kk = bid & 15, slot tid -> ONE f32x4 register stored
// for the whole sweep.
__global__ __launch_bounds__(256) void fused_kernel(
    const float* __restrict__ I, const float* __restrict__ Q,
    const float* __restrict__ ew, float* __restrict__ out, int P)
{
    const int tid = threadIdx.x;
    const int bid = blockIdx.x;
    const unsigned T    = gridDim.x * 256u;     // f32x4 grid stride
    const unsigned idx0 = bid * 256u + tid;

    // ---- Part A: patches [P,128,2] (8 MB) ----
    {
        f32x4* pout = reinterpret_cast<f32x4*>(out);
        const unsigned total = (unsigned)P * (PL / 2);   // f32x4 covers t,t+1
        for (unsigned idx = idx0; idx < total; idx += T) {
            int p = (int)(idx >> 6);
            int t = ((int)idx & 63) * 2;
            int src = p * STRIDE + t;
            f32x4 val = {I[src], Q[src], I[src + 1], Q[src + 1]};
            pout[idx] = val;
        }
    }

    // ---- Part B: this thread's single f32x4 of adj ----
    // element e = (kk*256 + tid)*4 + c -> row = kk*8 + (tid>>5), col = (tid&31)*4 + c
    const int kk  = bid & 15;
    const int row = kk * 8 + (tid >> 5);
    const int j0  = (tid & 31) * 4;
    f32x4 v = {0.f, 0.f, 0.f, 0.f};
#pragma unroll
    for (int c = 0; c < 4; ++c) {
        int j = j0 + c;
        int d = row - j; if (d < 0) d = -d;
        if (d > 0 && d <= WSZ) {
            v[c] = 1.0f / (1.0f + __expf(-ew[row * PL + j]));
        }
    }

    // ---- Part C: device-lockstep sweep; thread's target offset is invariant ----
    f32x4* aout = reinterpret_cast<f32x4*>(out + (size_t)P * PL * 2);
    const unsigned M = (unsigned)P * (PL * PL / 4);      // 31,993,856 for P=7811
    for (unsigned m = idx0; m < M; m += T) {
        aout[m] = v;
    }
}

extern "C" void kernel_launch(void* const* d_in, const int* in_sizes, int n_in,
                              void* d_out, int out_size, void* d_ws, size_t ws_size,
                              hipStream_t stream) {
    const float* I  = (const float*)d_in[0];
    const float* Q  = (const float*)d_in[1];
    const float* ew = (const float*)d_in[2];
    float* out = (float*)d_out;

    const int n = in_sizes[0];
    const int P = (n - PL) / STRIDE + 1;   // 7811 for L=500000

    // 512 blocks = 2 per CU (8 waves/CU); multiple of 16 keeps the
    // invariant-offset mapping exact.
    fused_kernel<<<512, 256, 0, stream>>>(I, Q, ew, out, P);
}

// Round 10
// 95.508 us; speedup vs baseline: 1.0878x; 1.0878x over previous
//
#include <hip/hip_runtime.h>

#define PL 128
#define STRIDE 64
#define WSZ 16

typedef float f32x4 __attribute__((ext_vector_type(4)));

// R8 fill-replica structure (grid 256 = 1 block/CU, lockstep 1 MB window,
// one invariant f32x4 per thread), single variable changed vs R8:
// Part C stores are NONTEMPORAL (write-around L2). Tests whether L2
// write-allocate eviction traffic is the remaining limiter vs the 6.9 TB/s
// fill rate. nt was previously only tested on chunked/strided structures.
__global__ __launch_bounds__(256) void fused_kernel(
    const float* __restrict__ I, const float* __restrict__ Q,
    const float* __restrict__ ew, float* __restrict__ out, int P)
{
    const int tid = threadIdx.x;
    const int bid = blockIdx.x;
    const unsigned T    = gridDim.x * 256u;     // 65536 f32x4 = 1 MB window
    const unsigned idx0 = bid * 256u + tid;

    // ---- Part A: patches [P,128,2] (8 MB) ----
    {
        f32x4* pout = reinterpret_cast<f32x4*>(out);
        const unsigned total = (unsigned)P * (PL / 2);   // f32x4 covers t,t+1
        for (unsigned idx = idx0; idx < total; idx += T) {
            int p = (int)(idx >> 6);
            int t = ((int)idx & 63) * 2;
            int src = p * STRIDE + t;
            f32x4 val = {I[src], Q[src], I[src + 1], Q[src + 1]};
            pout[idx] = val;
        }
    }

    // ---- Part B: this thread's single f32x4 of adj ----
    // element e = (kk*256 + tid)*4 + c -> row = kk*8 + (tid>>5), col = (tid&31)*4 + c
    const int kk  = bid & 15;
    const int row = kk * 8 + (tid >> 5);
    const int j0  = (tid & 31) * 4;
    f32x4 v = {0.f, 0.f, 0.f, 0.f};
#pragma unroll
    for (int c = 0; c < 4; ++c) {
        int j = j0 + c;
        int d = row - j; if (d < 0) d = -d;
        if (d > 0 && d <= WSZ) {
            v[c] = 1.0f / (1.0f + __expf(-ew[row * PL + j]));
        }
    }

    // ---- Part C: device-lockstep sweep, nontemporal stores ----
    f32x4* aout = reinterpret_cast<f32x4*>(out + (size_t)P * PL * 2);
    const unsigned M = (unsigned)P * (PL * PL / 4);      // 31,993,856 for P=7811
    for (unsigned m = idx0; m < M; m += T) {
        __builtin_nontemporal_store(v, &aout[m]);
    }
}

extern "C" void kernel_launch(void* const* d_in, const int* in_sizes, int n_in,
                              void* d_out, int out_size, void* d_ws, size_t ws_size,
                              hipStream_t stream) {
    const float* I  = (const float*)d_in[0];
    const float* Q  = (const float*)d_in[1];
    const float* ew = (const float*)d_in[2];
    float* out = (float*)d_out;

    const int n = in_sizes[0];
    const int P = (n - PL) / STRIDE + 1;   // 7811 for L=500000

    // 256 blocks = 1 per CU; multiple of 16 keeps the invariant-offset mapping.
    fused_kernel<<<256, 256, 0, stream>>>(I, Q, ew, out, P);
}